// Round 2
// baseline (1166.946 us; speedup 1.0000x reference)
//
#include <hip/hip_runtime.h>
#include <hip/hip_bf16.h>

#define TSTEPS 1024
#define NIN 128
#define NL 64
#define NH 128
#define NOUT 32
#define CH 16
#define NCHUNK (TSTEPS / CH)

typedef __attribute__((ext_vector_type(8))) short short8;
typedef __attribute__((ext_vector_type(4))) float f32x4;

__device__ inline int pk2(float x, float y) {
    __hip_bfloat162 h = __float22bfloat162_rn(make_float2(x, y));
    union { __hip_bfloat162 h; int i; } u;
    u.h = h;
    return u.i;
}

__device__ inline short8 pack8(float4 r0, float4 r1) {
    union { short8 s; int i[4]; } f;
    f.i[0] = pk2(r0.x, r0.y); f.i[1] = pk2(r0.z, r0.w);
    f.i[2] = pk2(r1.x, r1.y); f.i[3] = pk2(r1.z, r1.w);
    return f.s;
}

#define WG_BARRIER() asm volatile("s_waitcnt lgkmcnt(0)\n\ts_barrier" ::: "memory")

// ---------------------------------------------------------------------------
// Fused producer/consumer. Grid: 16 WGs x 512 thr. Each WG owns 16 batches.
//   waves 0..3 (consumers): the proven 4-wave M-split scan (2 barriers/step).
//     Wave w: H tiles {2w,2w+1}, Z tile {w}. u(t) read from LDS ring.
//   waves 4..7 (producers): stage u'(t)=C@s_t+h1 (bf16) for chunk ch+1 into
//     ubuf[(ch+1)&1] while consumers run chunk ch, matching every barrier.
// Barrier count: consumers 2*TSTEPS + 1 ; producers NCHUNK*2*CH + 1. Equal.
// ---------------------------------------------------------------------------
__launch_bounds__(512, 1)
__global__ void plrnn_fused(const float* __restrict__ input,
                            const float* __restrict__ A,
                            const float* __restrict__ W1,
                            const float* __restrict__ W2,
                            const float* __restrict__ h1,
                            const float* __restrict__ h2,
                            const float* __restrict__ C,
                            const float* __restrict__ Wout,
                            const float* __restrict__ bout,
                            float* __restrict__ out) {
    // u ring: [2][tl][b][72 shorts] (64 used, plain latent order, pad 72)
    __shared__ __attribute__((aligned(16))) unsigned short ubuf[2][CH * 16 * 72];
    __shared__ __attribute__((aligned(16))) unsigned short zbuf[16 * 72];
    __shared__ __attribute__((aligned(16))) unsigned short hbuf[16 * 136];

    const int lane = threadIdx.x & 63;
    const int w = threadIdx.x >> 6;
    const int c = lane & 15;   // batch column within group
    const int q = lane >> 4;   // quad
    const int bbase = blockIdx.x * 16;

    if (w < 4) {
        // ================= consumers: 4-wave M-split scan =================
        __builtin_amdgcn_s_setprio(1);

        short8 aw2[2][2];   // W2 A-frags: H tiles 2w,2w+1 ; K=64 (2 frags)
        #pragma unroll
        for (int i = 0; i < 2; ++i)
            #pragma unroll
            for (int kt = 0; kt < 2; ++kt) {
                const float* p = W2 + ((2 * w + i) * 16 + c) * NL + kt * 32 + q * 8;
                aw2[i][kt] = pack8(*(const float4*)p, *(const float4*)(p + 4));
            }
        short8 aw1[4];      // W1 A-frags: Z tile w ; K=128 (4 frags)
        #pragma unroll
        for (int kt = 0; kt < 4; ++kt) {
            const float* p = W1 + (w * 16 + c) * NH + kt * 32 + q * 8;
            aw1[kt] = pack8(*(const float4*)p, *(const float4*)(p + 4));
        }
        f32x4 h2f[2];
        #pragma unroll
        for (int i = 0; i < 2; ++i)
            h2f[i] = *(const f32x4*)(h2 + (2 * w + i) * 16 + q * 4);
        const f32x4 af = *(const f32x4*)(A + w * 16 + q * 4);

        f32x4 zf = {0.f, 0.f, 0.f, 0.f};

        for (int t = 0; t < TSTEPS; ++t) {
            // ---- publish z slice (latents [16w,16w+16)) ----
            *(int2*)&zbuf[c * 72 + w * 16 + q * 4] =
                make_int2(pk2(zf[0], zf[1]), pk2(zf[2], zf[3]));
            WG_BARRIER();   // B1: z visible; ubuf[(t>>4)&1] valid for this chunk
            short8 bz0 = *(short8*)&zbuf[c * 72 + q * 8];
            short8 bz1 = *(short8*)&zbuf[c * 72 + 32 + q * 8];
            int2 ur = *(const int2*)&ubuf[(t >> 4) & 1]
                                         [((t & 15) * 16 + c) * 72 + w * 16 + q * 4];

            // ---- MFMA1: H rows [32w,32w+32) = relu(W2 @ Z + h2) ----
            #pragma unroll
            for (int i = 0; i < 2; ++i) {
                f32x4 acc = __builtin_amdgcn_mfma_f32_16x16x32_bf16(aw2[i][0], bz0, h2f[i], 0, 0, 0);
                acc = __builtin_amdgcn_mfma_f32_16x16x32_bf16(aw2[i][1], bz1, acc, 0, 0, 0);
                *(int2*)&hbuf[c * 136 + (2 * w + i) * 16 + q * 4] =
                    make_int2(pk2(fmaxf(acc[0], 0.f), fmaxf(acc[1], 0.f)),
                              pk2(fmaxf(acc[2], 0.f), fmaxf(acc[3], 0.f)));
            }
            // cin = A*z + u  (off the critical path: before B2)
            f32x4 cin;
            cin[0] = fmaf(zf[0], af[0], __int_as_float(ur.x << 16));
            cin[1] = fmaf(zf[1], af[1], __int_as_float(ur.x & 0xffff0000));
            cin[2] = fmaf(zf[2], af[2], __int_as_float(ur.y << 16));
            cin[3] = fmaf(zf[3], af[3], __int_as_float(ur.y & 0xffff0000));

            WG_BARRIER();   // B2: H visible
            short8 bh0 = *(short8*)&hbuf[c * 136 + q * 8];
            short8 bh1 = *(short8*)&hbuf[c * 136 + 32 + q * 8];
            short8 bh2 = *(short8*)&hbuf[c * 136 + 64 + q * 8];
            short8 bh3 = *(short8*)&hbuf[c * 136 + 96 + q * 8];

            // ---- MFMA2: Z' rows [16w,16w+16) = clip(cin + W1 @ H) ----
            f32x4 acc = __builtin_amdgcn_mfma_f32_16x16x32_bf16(aw1[0], bh0, cin, 0, 0, 0);
            acc = __builtin_amdgcn_mfma_f32_16x16x32_bf16(aw1[1], bh1, acc, 0, 0, 0);
            acc = __builtin_amdgcn_mfma_f32_16x16x32_bf16(aw1[2], bh2, acc, 0, 0, 0);
            acc = __builtin_amdgcn_mfma_f32_16x16x32_bf16(aw1[3], bh3, acc, 0, 0, 0);
            #pragma unroll
            for (int e = 0; e < 4; ++e)
                zf[e] = fminf(fmaxf(acc[e], -5.f), 5.f);
        }

        // ---- epilogue: out = Wout @ Z + bout (waves 0,1) ----
        *(int2*)&zbuf[c * 72 + w * 16 + q * 4] =
            make_int2(pk2(zf[0], zf[1]), pk2(zf[2], zf[3]));
        WG_BARRIER();
        if (w < 2) {
            short8 fz0 = *(short8*)&zbuf[c * 72 + q * 8];
            short8 fz1 = *(short8*)&zbuf[c * 72 + 32 + q * 8];
            const float* p0 = Wout + (w * 16 + c) * NL + q * 8;
            short8 fa = pack8(*(const float4*)p0, *(const float4*)(p0 + 4));
            short8 fb = pack8(*(const float4*)(p0 + 32), *(const float4*)(p0 + 36));
            f32x4 cb = *(const f32x4*)(bout + w * 16 + q * 4);
            f32x4 acc = __builtin_amdgcn_mfma_f32_16x16x32_bf16(fa, fz0, cb, 0, 0, 0);
            acc = __builtin_amdgcn_mfma_f32_16x16x32_bf16(fb, fz1, acc, 0, 0, 0);
            *(f32x4*)&out[(bbase + c) * NOUT + w * 16 + q * 4] = acc;
        }
    } else {
        // ================= producers (waves 4..7) =================
        const int p = w - 4;                 // each owns rows 4p..4p+3 of a chunk
        short8 cA[4][4];
        #pragma unroll
        for (int mt = 0; mt < 4; ++mt)
            #pragma unroll
            for (int kf = 0; kf < 4; ++kf) {
                const float* pp = C + (mt * 16 + c) * NIN + kf * 32 + q * 8;
                cA[mt][kf] = pack8(*(const float4*)pp, *(const float4*)(pp + 4));
            }
        f32x4 h1f[4];
        #pragma unroll
        for (int mt = 0; mt < 4; ++mt) h1f[mt] = *(const f32x4*)(h1 + mt * 16 + q * 4);

        float4 rawA[8], rawB[8];

#define P_ISSUE(ck, r, raw) do {                                               \
        const float* sr_ = input +                                             \
            ((size_t)(bbase + c) * TSTEPS + (ck) * CH + 4 * p + (r)) * NIN;    \
        _Pragma("unroll")                                                      \
        for (int kf = 0; kf < 4; ++kf) {                                       \
            raw[2 * kf]     = *(const float4*)(sr_ + kf * 32 + q * 8);         \
            raw[2 * kf + 1] = *(const float4*)(sr_ + kf * 32 + q * 8 + 4);     \
        } } while (0)

#define P_FLUSH(ck, r, raw) do {                                               \
        short8 bf_[4];                                                         \
        _Pragma("unroll")                                                      \
        for (int kf = 0; kf < 4; ++kf)                                         \
            bf_[kf] = pack8(raw[2 * kf], raw[2 * kf + 1]);                     \
        unsigned short* orow_ =                                                \
            &ubuf[(ck) & 1][((4 * p + (r)) * 16 + c) * 72 + q * 4];            \
        _Pragma("unroll")                                                      \
        for (int mt = 0; mt < 4; ++mt) {                                       \
            f32x4 acc_ = __builtin_amdgcn_mfma_f32_16x16x32_bf16(              \
                cA[mt][0], bf_[0], h1f[mt], 0, 0, 0);                          \
            acc_ = __builtin_amdgcn_mfma_f32_16x16x32_bf16(cA[mt][1], bf_[1], acc_, 0, 0, 0); \
            acc_ = __builtin_amdgcn_mfma_f32_16x16x32_bf16(cA[mt][2], bf_[2], acc_, 0, 0, 0); \
            acc_ = __builtin_amdgcn_mfma_f32_16x16x32_bf16(cA[mt][3], bf_[3], acc_, 0, 0, 0); \
            *(int2*)(orow_ + mt * 16) =                                        \
                make_int2(pk2(acc_[0], acc_[1]), pk2(acc_[2], acc_[3]));       \
        } } while (0)

        // prologue: fully stage chunk 0 (2-row software pipeline)
        P_ISSUE(0, 0, rawA); P_ISSUE(0, 1, rawB);
        P_FLUSH(0, 0, rawA); P_ISSUE(0, 2, rawA);
        P_FLUSH(0, 1, rawB); P_ISSUE(0, 3, rawB);
        P_FLUSH(0, 2, rawA); P_FLUSH(0, 3, rawB);

        for (int ch = 0; ch < NCHUNK; ++ch) {
            const bool more = (ch + 1 < NCHUNK);
            for (int i = 0; i < 2 * CH; ++i) {
                WG_BARRIER();
                if (more) {
                    if (i == 2)       { P_ISSUE(ch + 1, 0, rawA); }
                    else if (i == 8)  { P_FLUSH(ch + 1, 0, rawA); P_ISSUE(ch + 1, 1, rawB); }
                    else if (i == 14) { P_FLUSH(ch + 1, 1, rawB); P_ISSUE(ch + 1, 2, rawA); }
                    else if (i == 20) { P_FLUSH(ch + 1, 2, rawA); P_ISSUE(ch + 1, 3, rawB); }
                    else if (i == 26) { P_FLUSH(ch + 1, 3, rawB); }
                }
            }
        }
        WG_BARRIER();   // match consumer epilogue barrier
#undef P_ISSUE
#undef P_FLUSH
    }
}

extern "C" void kernel_launch(void* const* d_in, const int* in_sizes, int n_in,
                              void* d_out, int out_size, void* d_ws, size_t ws_size,
                              hipStream_t stream) {
    const float* input = (const float*)d_in[0];
    const float* A     = (const float*)d_in[1];
    const float* W1    = (const float*)d_in[2];
    const float* W2    = (const float*)d_in[3];
    const float* h1    = (const float*)d_in[4];
    const float* h2    = (const float*)d_in[5];
    const float* C     = (const float*)d_in[6];
    const float* Wout  = (const float*)d_in[7];
    const float* bout  = (const float*)d_in[8];
    float* out = (float*)d_out;

    plrnn_fused<<<dim3(16), dim3(512), 0, stream>>>(
        input, A, W1, W2, h1, h2, C, Wout, bout, out);
}

// Round 3
// 890.681 us; speedup vs baseline: 1.3102x; 1.3102x over previous
//
#include <hip/hip_runtime.h>
#include <hip/hip_bf16.h>

#define TSTEPS 1024
#define NIN 128
#define NL 64
#define NH 128
#define NOUT 32

typedef __attribute__((ext_vector_type(8))) short short8;
typedef __attribute__((ext_vector_type(4))) float f32x4;

__device__ inline int pk2(float x, float y) {
    __hip_bfloat162 h = __float22bfloat162_rn(make_float2(x, y));
    union { __hip_bfloat162 h; int i; } u;
    u.h = h;
    return u.i;
}
__device__ inline short bf1(float x) {
    __hip_bfloat16 h = __float2bfloat16(x);
    union { __hip_bfloat16 h; short s; } u;
    u.h = h;
    return u.s;
}
__device__ inline short8 pack8(float4 r0, float4 r1) {
    union { short8 s; int i[4]; } f;
    f.i[0] = pk2(r0.x, r0.y); f.i[1] = pk2(r0.z, r0.w);
    f.i[2] = pk2(r1.x, r1.y); f.i[3] = pk2(r1.z, r1.w);
    return f.s;
}

#define WG_BARRIER() asm volatile("s_waitcnt lgkmcnt(0)\n\ts_barrier" ::: "memory")

// ---------------------------------------------------------------------------
// Pass 1: u'[t][b][l] = bf16( C[l,:]·s[b,t,:] + h1[l] )   — verbatim round-0.
// ---------------------------------------------------------------------------
__launch_bounds__(256, 1)
__global__ void ugemm_mfma(const float* __restrict__ input,
                           const float* __restrict__ C,
                           const float* __restrict__ h1,
                           unsigned short* __restrict__ u16) {
    const int lane = threadIdx.x & 63;
    const int wv   = threadIdx.x >> 6;
    const int c = lane & 15;
    const int q = lane >> 4;
    const long wbase = ((long)blockIdx.x * 4 + wv) * 128;  // first row (b*1024+t)

    short8 cA[4][4];
    #pragma unroll
    for (int mt = 0; mt < 4; ++mt)
        #pragma unroll
        for (int kf = 0; kf < 4; ++kf) {
            const float* p = C + (mt * 16 + c) * NIN + kf * 32 + q * 8;
            cA[mt][kf] = pack8(*(const float4*)p, *(const float4*)(p + 4));
        }
    f32x4 h1f[4];
    #pragma unroll
    for (int mt = 0; mt < 4; ++mt)
        h1f[mt] = *(const f32x4*)(h1 + mt * 16 + q * 4);

    float4 raw[8], rawn[8];
    {
        const float* sr = input + (wbase + c) * NIN;
        #pragma unroll
        for (int kf = 0; kf < 4; ++kf) {
            raw[2*kf]   = *(const float4*)(sr + kf * 32 + q * 8);
            raw[2*kf+1] = *(const float4*)(sr + kf * 32 + q * 8 + 4);
        }
    }

    for (int it = 0; it < 8; ++it) {
        if (it < 7) {
            const float* sr = input + (wbase + (it + 1) * 16 + c) * NIN;
            #pragma unroll
            for (int kf = 0; kf < 4; ++kf) {
                rawn[2*kf]   = *(const float4*)(sr + kf * 32 + q * 8);
                rawn[2*kf+1] = *(const float4*)(sr + kf * 32 + q * 8 + 4);
            }
        }
        short8 bf[4];
        #pragma unroll
        for (int kf = 0; kf < 4; ++kf)
            bf[kf] = pack8(raw[2*kf], raw[2*kf+1]);
        long rr = wbase + it * 16 + c;
        int b = (int)(rr >> 10), t = (int)(rr & 1023);
        unsigned short* ubase = u16 + ((size_t)t * 256 + b) * 64 + q * 4;
        #pragma unroll
        for (int mt = 0; mt < 4; ++mt) {
            f32x4 acc = __builtin_amdgcn_mfma_f32_16x16x32_bf16(cA[mt][0], bf[0], h1f[mt], 0, 0, 0);
            acc = __builtin_amdgcn_mfma_f32_16x16x32_bf16(cA[mt][1], bf[1], acc, 0, 0, 0);
            acc = __builtin_amdgcn_mfma_f32_16x16x32_bf16(cA[mt][2], bf[2], acc, 0, 0, 0);
            acc = __builtin_amdgcn_mfma_f32_16x16x32_bf16(cA[mt][3], bf[3], acc, 0, 0, 0);
            *(int2*)(ubase + mt * 16) =
                make_int2(pk2(acc[0], acc[1]), pk2(acc[2], acc[3]));
        }
        #pragma unroll
        for (int j = 0; j < 8; ++j) raw[j] = rawn[j];
    }
}

// ---------------------------------------------------------------------------
// Pass 2: phase-shifted two-group MFMA scan. Grid 8 WGs x 256 thr (4 waves).
// WG owns 32 batches: group A = bbase..+15, group B = bbase+16..+31, half a
// step out of phase. Each inter-barrier region: MFMA2(one group) + MFMA1
// (other group) — independent streams hide each other's LDS/MFMA latency.
// Per-group op order identical to the proven 4-wave scan.
// ---------------------------------------------------------------------------
__launch_bounds__(256, 1)
__global__ void plrnn_scan2(const float* __restrict__ A,
                            const float* __restrict__ W1,
                            const float* __restrict__ W2,
                            const float* __restrict__ h2,
                            const unsigned short* __restrict__ u16,
                            const float* __restrict__ Wout,
                            const float* __restrict__ bout,
                            float* __restrict__ out) {
    __shared__ __attribute__((aligned(16))) unsigned short zbufA[16 * 72];
    __shared__ __attribute__((aligned(16))) unsigned short zbufB[16 * 72];
    __shared__ __attribute__((aligned(16))) unsigned short hbufA[16 * 136];
    __shared__ __attribute__((aligned(16))) unsigned short hbufB[16 * 136];

    const int lane = threadIdx.x & 63;
    const int w    = threadIdx.x >> 6;     // wave 0..3
    const int c = lane & 15;               // batch col
    const int q = lane >> 4;               // quad
    const int bbase = blockIdx.x * 32;

    // ---- shared static weight fragments (same as proven scan) ----
    short8 aw2[2][2];   // H tiles 2w,2w+1 ; K=64
    #pragma unroll
    for (int i = 0; i < 2; ++i)
        #pragma unroll
        for (int kt = 0; kt < 2; ++kt) {
            const float* p = W2 + ((2*w + i) * 16 + c) * NL + kt * 32 + q * 8;
            aw2[i][kt] = pack8(*(const float4*)p, *(const float4*)(p + 4));
        }
    short8 aw1[4];      // Z tile w ; K=128
    #pragma unroll
    for (int kt = 0; kt < 4; ++kt) {
        const float* p = W1 + (w * 16 + c) * NH + kt * 32 + q * 8;
        aw1[kt] = pack8(*(const float4*)p, *(const float4*)(p + 4));
    }
    f32x4 h2f[2];
    #pragma unroll
    for (int i = 0; i < 2; ++i)
        h2f[i] = *(const f32x4*)(h2 + (2*w + i) * 16 + q * 4);
    const f32x4 af = *(const f32x4*)(A + w * 16 + q * 4);

    f32x4 zfA = {0.f, 0.f, 0.f, 0.f};
    f32x4 zfB = {0.f, 0.f, 0.f, 0.f};

    // u' streams (layout identical to proven scan); stride/t = 16384 shorts
    const unsigned short* ubA = u16 + ((size_t)(bbase + c)) * 64 + w * 16 + q * 4;
    const unsigned short* ubB = u16 + ((size_t)(bbase + 16 + c)) * 64 + w * 16 + q * 4;
    int2 ucurA = *(const int2*)ubA;
    int2 unxA  = *(const int2*)(ubA + 16384);
    int2 ucurB = *(const int2*)ubB;
    int2 unxB  = *(const int2*)(ubB + 16384);

    // ---- prologue: publish z(0)=0 for both groups ----
    *(int2*)&zbufA[c * 72 + w * 16 + q * 4] = make_int2(0, 0);
    *(int2*)&zbufB[c * 72 + w * 16 + q * 4] = make_int2(0, 0);
    WG_BARRIER();

    // ---- region 0: MFMA1_A(0) ----
    {
        short8 bz0 = *(short8*)&zbufA[c * 72 + q * 8];
        short8 bz1 = *(short8*)&zbufA[c * 72 + 32 + q * 8];
        #pragma unroll
        for (int i = 0; i < 2; ++i) {
            f32x4 acc = __builtin_amdgcn_mfma_f32_16x16x32_bf16(aw2[i][0], bz0, h2f[i], 0, 0, 0);
            acc = __builtin_amdgcn_mfma_f32_16x16x32_bf16(aw2[i][1], bz1, acc, 0, 0, 0);
            *(int2*)&hbufA[c * 136 + (2*w + i) * 16 + q * 4] =
                make_int2(pk2(fmaxf(acc[0], 0.f), fmaxf(acc[1], 0.f)),
                          pk2(fmaxf(acc[2], 0.f), fmaxf(acc[3], 0.f)));
        }
    }
    WG_BARRIER();

    for (int t = 0; t < TSTEPS; ++t) {
        // ================= region 2t+1: MFMA2_A(t) + MFMA1_B(t) =================
        {
            // issue all LDS reads up front
            short8 bh0 = *(short8*)&hbufA[c * 136 + q * 8];
            short8 bh1 = *(short8*)&hbufA[c * 136 + 32 + q * 8];
            short8 bh2 = *(short8*)&hbufA[c * 136 + 64 + q * 8];
            short8 bh3 = *(short8*)&hbufA[c * 136 + 96 + q * 8];
            short8 bz0 = *(short8*)&zbufB[c * 72 + q * 8];
            short8 bz1 = *(short8*)&zbufB[c * 72 + 32 + q * 8];

            int tp = (t + 2 < TSTEPS) ? t + 2 : TSTEPS - 1;
            int2 upf = *(const int2*)(ubA + (size_t)tp * 16384);

            // --- MFMA2_A: z_A' = clip(A.z + u' + W1 @ H_A) ---
            f32x4 cin;
            cin[0] = fmaf(zfA[0], af[0], __int_as_float(ucurA.x << 16));
            cin[1] = fmaf(zfA[1], af[1], __int_as_float(ucurA.x & 0xffff0000));
            cin[2] = fmaf(zfA[2], af[2], __int_as_float(ucurA.y << 16));
            cin[3] = fmaf(zfA[3], af[3], __int_as_float(ucurA.y & 0xffff0000));
            f32x4 acc = __builtin_amdgcn_mfma_f32_16x16x32_bf16(aw1[0], bh0, cin, 0, 0, 0);
            acc = __builtin_amdgcn_mfma_f32_16x16x32_bf16(aw1[1], bh1, acc, 0, 0, 0);
            acc = __builtin_amdgcn_mfma_f32_16x16x32_bf16(aw1[2], bh2, acc, 0, 0, 0);
            acc = __builtin_amdgcn_mfma_f32_16x16x32_bf16(aw1[3], bh3, acc, 0, 0, 0);
            #pragma unroll
            for (int e = 0; e < 4; ++e)
                zfA[e] = fminf(fmaxf(acc[e], -5.f), 5.f);
            *(int2*)&zbufA[c * 72 + w * 16 + q * 4] =
                make_int2(pk2(zfA[0], zfA[1]), pk2(zfA[2], zfA[3]));

            // --- MFMA1_B: H_B = relu(W2 @ z_B + h2) ---
            #pragma unroll
            for (int i = 0; i < 2; ++i) {
                f32x4 ah = __builtin_amdgcn_mfma_f32_16x16x32_bf16(aw2[i][0], bz0, h2f[i], 0, 0, 0);
                ah = __builtin_amdgcn_mfma_f32_16x16x32_bf16(aw2[i][1], bz1, ah, 0, 0, 0);
                *(int2*)&hbufB[c * 136 + (2*w + i) * 16 + q * 4] =
                    make_int2(pk2(fmaxf(ah[0], 0.f), fmaxf(ah[1], 0.f)),
                              pk2(fmaxf(ah[2], 0.f), fmaxf(ah[3], 0.f)));
            }
            ucurA = unxA;
            unxA  = upf;
        }
        WG_BARRIER();

        // ================= region 2t+2: MFMA2_B(t) + MFMA1_A(t+1) =================
        {
            short8 bh0 = *(short8*)&hbufB[c * 136 + q * 8];
            short8 bh1 = *(short8*)&hbufB[c * 136 + 32 + q * 8];
            short8 bh2 = *(short8*)&hbufB[c * 136 + 64 + q * 8];
            short8 bh3 = *(short8*)&hbufB[c * 136 + 96 + q * 8];
            short8 bz0 = *(short8*)&zbufA[c * 72 + q * 8];
            short8 bz1 = *(short8*)&zbufA[c * 72 + 32 + q * 8];

            int tp = (t + 2 < TSTEPS) ? t + 2 : TSTEPS - 1;
            int2 upf = *(const int2*)(ubB + (size_t)tp * 16384);

            // --- MFMA2_B ---
            f32x4 cin;
            cin[0] = fmaf(zfB[0], af[0], __int_as_float(ucurB.x << 16));
            cin[1] = fmaf(zfB[1], af[1], __int_as_float(ucurB.x & 0xffff0000));
            cin[2] = fmaf(zfB[2], af[2], __int_as_float(ucurB.y << 16));
            cin[3] = fmaf(zfB[3], af[3], __int_as_float(ucurB.y & 0xffff0000));
            f32x4 acc = __builtin_amdgcn_mfma_f32_16x16x32_bf16(aw1[0], bh0, cin, 0, 0, 0);
            acc = __builtin_amdgcn_mfma_f32_16x16x32_bf16(aw1[1], bh1, acc, 0, 0, 0);
            acc = __builtin_amdgcn_mfma_f32_16x16x32_bf16(aw1[2], bh2, acc, 0, 0, 0);
            acc = __builtin_amdgcn_mfma_f32_16x16x32_bf16(aw1[3], bh3, acc, 0, 0, 0);
            #pragma unroll
            for (int e = 0; e < 4; ++e)
                zfB[e] = fminf(fmaxf(acc[e], -5.f), 5.f);
            *(int2*)&zbufB[c * 72 + w * 16 + q * 4] =
                make_int2(pk2(zfB[0], zfB[1]), pk2(zfB[2], zfB[3]));

            // --- MFMA1_A(t+1) (at t=1023 this is dead work, kept for uniformity) ---
            #pragma unroll
            for (int i = 0; i < 2; ++i) {
                f32x4 ah = __builtin_amdgcn_mfma_f32_16x16x32_bf16(aw2[i][0], bz0, h2f[i], 0, 0, 0);
                ah = __builtin_amdgcn_mfma_f32_16x16x32_bf16(aw2[i][1], bz1, ah, 0, 0, 0);
                *(int2*)&hbufA[c * 136 + (2*w + i) * 16 + q * 4] =
                    make_int2(pk2(fmaxf(ah[0], 0.f), fmaxf(ah[1], 0.f)),
                              pk2(fmaxf(ah[2], 0.f), fmaxf(ah[3], 0.f)));
            }
            ucurB = unxB;
            unxB  = upf;
        }
        WG_BARRIER();
    }

    // ---- epilogue: out = Wout @ z + bout ; waves 0,1 -> A, waves 2,3 -> B ----
    {
        const int mt = w & 1;
        const unsigned short* zb = (w < 2) ? zbufA : zbufB;
        const int boff = (w < 2) ? 0 : 16;
        short8 fz0 = *(short8*)&zb[c * 72 + q * 8];
        short8 fz1 = *(short8*)&zb[c * 72 + 32 + q * 8];
        const float* p0 = Wout + (mt * 16 + c) * NL + q * 8;
        short8 fa = pack8(*(const float4*)p0, *(const float4*)(p0 + 4));
        short8 fb = pack8(*(const float4*)(p0 + 32), *(const float4*)(p0 + 36));
        f32x4 cb = *(const f32x4*)(bout + mt * 16 + q * 4);
        f32x4 acc = __builtin_amdgcn_mfma_f32_16x16x32_bf16(fa, fz0, cb, 0, 0, 0);
        acc = __builtin_amdgcn_mfma_f32_16x16x32_bf16(fb, fz1, acc, 0, 0, 0);
        *(f32x4*)&out[(bbase + boff + c) * NOUT + mt * 16 + q * 4] = acc;
    }
}

extern "C" void kernel_launch(void* const* d_in, const int* in_sizes, int n_in,
                              void* d_out, int out_size, void* d_ws, size_t ws_size,
                              hipStream_t stream) {
    const float* input = (const float*)d_in[0];
    const float* A     = (const float*)d_in[1];
    const float* W1    = (const float*)d_in[2];
    const float* W2    = (const float*)d_in[3];
    const float* h1    = (const float*)d_in[4];
    const float* h2    = (const float*)d_in[5];
    const float* C     = (const float*)d_in[6];
    const float* Wout  = (const float*)d_in[7];
    const float* bout  = (const float*)d_in[8];
    float* out = (float*)d_out;

    unsigned short* u16 = (unsigned short*)d_ws;   // 256*1024*64 bf16 = 33.5 MB

    ugemm_mfma<<<dim3(512), dim3(256), 0, stream>>>(input, C, h1, u16);
    plrnn_scan2<<<dim3(8), dim3(256), 0, stream>>>(
        A, W1, W2, h2, u16, Wout, bout, out);
}